// Round 14
// baseline (261.257 us; speedup 1.0000x reference)
//
#include <hip/hip_runtime.h>
#include <hip/hip_bf16.h>
#include <cstdint>
#include <cmath>

// Problem constants
#define B_   2
#define S_   2048
#define H_   2048
#define NH_  32
#define NKV_ 8
#define HD_  64
#define CSTR 3072   // row stride of the concatenated QKV output [4096, 3072]

using bf16x8 = __attribute__((ext_vector_type(8))) short;
using f32x4  = __attribute__((ext_vector_type(4))) float;

#define MFMA16(a, b, c) __builtin_amdgcn_mfma_f32_16x16x32_bf16((a), (b), (c), 0, 0, 0)

__device__ __forceinline__ short f2bf(float f) {   // round-nearest-even
  uint32_t u = __float_as_uint(f);
  uint32_t r = (u + 0x7fffu + ((u >> 16) & 1u)) >> 16;
  return (short)r;
}
__device__ __forceinline__ float bf2f(short s) {
  return __uint_as_float(((uint32_t)(uint16_t)s) << 16);
}
// packed 2xf32 -> 2xbf16 (hardware op when available)
__device__ __forceinline__ uint32_t f2bf_pk(float a, float b) {
#if __has_builtin(__builtin_amdgcn_cvt_pk_bf16_f32)
  auto r = __builtin_amdgcn_cvt_pk_bf16_f32(a, b);
  uint32_t u; __builtin_memcpy(&u, &r, sizeof(u));
  return u;
#else
  uint32_t ua = (__float_as_uint(a) + 0x8000u) >> 16;
  uint32_t ub = (__float_as_uint(b) + 0x8000u) >> 16;
  return ua | (ub << 16);
#endif
}
// raw v_exp_f32 (2^x)
__device__ __forceinline__ float fast_exp2(float x) {
#if __has_builtin(__builtin_amdgcn_exp2f)
  return __builtin_amdgcn_exp2f(x);
#else
  return exp2f(x);
#endif
}

__device__ __forceinline__ void gload_lds16(const void* g, void* l) {
  __builtin_amdgcn_global_load_lds((const __attribute__((address_space(1))) void*)g,
                                   (__attribute__((address_space(3))) void*)l, 16, 0, 0);
}

// ---------------- fused fp32 -> bf16 convert for all 5 tensors ------------------
struct Cvt5Args {
  const float *s0, *s1, *s2, *s3, *s4;
  short *d0, *d1, *d2, *d3, *d4;
};
#define CV0 2097152             // hs      (float4 units)
#define CV1 (CV0 + 1048576)     // Wq
#define CV2 (CV1 + 262144)      // Wk
#define CV3 (CV2 + 262144)      // Wv
#define CV4 (CV3 + 1048576)     // Wo -> total 4718592
__global__ void cvt5_kernel(Cvt5Args a) {
  int i = blockIdx.x * blockDim.x + threadIdx.x;
  const float* s; short* d; int off;
  if      (i < CV0) { s = a.s0; d = a.d0; off = i; }
  else if (i < CV1) { s = a.s1; d = a.d1; off = i - CV0; }
  else if (i < CV2) { s = a.s2; d = a.d2; off = i - CV1; }
  else if (i < CV3) { s = a.s3; d = a.d3; off = i - CV2; }
  else              { s = a.s4; d = a.d4; off = i - CV3; }
  const float4 v = ((const float4*)s)[off];
  uint2 o;
  o.x = (uint32_t)(uint16_t)f2bf(v.x) | ((uint32_t)(uint16_t)f2bf(v.y) << 16);
  o.y = (uint32_t)(uint16_t)f2bf(v.z) | ((uint32_t)(uint16_t)f2bf(v.w) << 16);
  ((uint2*)d)[off] = o;
}

// ---------------- 128x192 QKV-cat GEMM: grid 16x32 = 512 blocks = 2/CU ---------
// Ccat[4096,3072] = X[4096,2048] * Wcat[3072,2048]^T. BK=64, 512 threads =
// 8 waves (2M x 4N); per wave 64x48 output = 4x3 16x16 frags (48 acc VGPR).
// LDS = A 2x16K + B 2x24K = EXACTLY 80 KiB -> 2 blocks/CU (4 waves/SIMD).
// R7-verified: 52 us, MfmaUtil ~41, 990 TF. Cross-block overlap (m114) covers
// the end-of-tile vmcnt(0) drain. Protocol & XOR swizzle unchanged.
__global__ __launch_bounds__(512, 4) void gemm_qkvcat(
    const short* __restrict__ A, const short* __restrict__ Bcat,
    short* __restrict__ Ccat)
{
  __shared__ __align__(16) short As[2][128 * 64];   // 32 KiB
  __shared__ __align__(16) short Bs[2][192 * 64];   // 48 KiB

  const long tileM = (long)blockIdx.y * 128;
  const long tileN = (long)blockIdx.x * 192;
  const int  K = 2048;

  const int tid  = threadIdx.x;
  const int lane = tid & 63;
  const int quad = lane >> 4;
  const int l15  = lane & 15;
  const int wave = tid >> 6;
  const int wm   = (wave >> 2) * 64;      // 0 / 64
  const int wn   = (wave & 3) * 48;       // 0..144 (multiple of 16)
  const int xsw  = l15 & 7;

  f32x4 acc[4][3];
#pragma unroll
  for (int i = 0; i < 4; ++i)
#pragma unroll
    for (int j = 0; j < 3; ++j) acc[i][j] = f32x4{0.f, 0.f, 0.f, 0.f};

  // Staging: thread c = tid + 512p covers row c>>3, LDS chunk c&7 (linear dest).
  // Global source chunk = swizzle inverse. A: 2 passes (128 rows), B: 3 (192).
  const int cS = (tid & 7) ^ ((tid >> 3) & 7);
  const short* gA[2]; const short* gB[3];
#pragma unroll
  for (int p = 0; p < 2; ++p)
    gA[p] = A + (tileM + (tid >> 3) + 64 * p) * K + cS * 8;
#pragma unroll
  for (int p = 0; p < 3; ++p)
    gB[p] = Bcat + (tileN + (tid >> 3) + 64 * p) * K + cS * 8;

  auto stage = [&](int buf, int t) {
    const long ko = (long)t * 64;
    short* la = &As[buf][0];
    short* lb = &Bs[buf][0];
#pragma unroll
    for (int p = 0; p < 2; ++p)
      gload_lds16(gA[p] + ko, la + (tid + p * 512) * 8);
#pragma unroll
    for (int p = 0; p < 3; ++p)
      gload_lds16(gB[p] + ko, lb + (tid + p * 512) * 8);
  };

  const int NT = K / 64;                       // 32
  stage(0, 0);
  asm volatile("s_waitcnt vmcnt(0)" ::: "memory");
  asm volatile("s_barrier" ::: "memory");

  bf16x8 af[2][2], bfr[3][2];

  auto ldA = [&](const short* Ab, int half) {
#pragma unroll
    for (int m = 0; m < 2; ++m) {
      const int r = wm + (half * 2 + m) * 16 + l15;
#pragma unroll
      for (int kk = 0; kk < 2; ++kk)
        af[m][kk] = *(const bf16x8*)&Ab[r * 64 + (((kk * 4 + quad) ^ xsw) << 3)];
    }
  };
  auto ldB = [&](const short* Bb) {
#pragma unroll
    for (int n = 0; n < 3; ++n) {
      const int r = wn + n * 16 + l15;
#pragma unroll
      for (int kk = 0; kk < 2; ++kk)
        bfr[n][kk] = *(const bf16x8*)&Bb[r * 64 + (((kk * 4 + quad) ^ xsw) << 3)];
    }
  };
  auto mma = [&](int half) {
    __builtin_amdgcn_s_setprio(1);
#pragma unroll
    for (int m = 0; m < 2; ++m)
#pragma unroll
      for (int n = 0; n < 3; ++n)
#pragma unroll
        for (int kk = 0; kk < 2; ++kk)
          acc[half * 2 + m][n] = MFMA16(af[m][kk], bfr[n][kk], acc[half * 2 + m][n]);
    __builtin_amdgcn_s_setprio(0);
  };

  for (int t = 0; t < NT; ++t) {
    const int cur = t & 1;
    const short* Ab = &As[cur][0];
    const short* Bb = &Bs[cur][0];

    // phase 0: stage next tile, mf-half 0 (B loaded once, reused in half 1)
    if (t + 1 < NT) stage(cur ^ 1, t + 1);
    ldB(Bb); ldA(Ab, 0); mma(0);
    asm volatile("s_barrier" ::: "memory");
    // phase 1: mf-half 1
    ldA(Ab, 1); mma(1);
    asm volatile("s_waitcnt vmcnt(0)" ::: "memory");    // next-tile DMA landed
    asm volatile("s_waitcnt lgkmcnt(0)" ::: "memory");  // my reads of slot cur done
    asm volatile("s_barrier" ::: "memory");             // release slot cur
  }

#pragma unroll
  for (int i = 0; i < 4; ++i)
#pragma unroll
    for (int j = 0; j < 3; ++j)
#pragma unroll
      for (int r = 0; r < 4; ++r) {
        long row = tileM + wm + i * 16 + quad * 4 + r;
        long col = tileN + wn + j * 16 + l15;
        Ccat[row * CSTR + col] = f2bf(acc[i][j][r]);
      }
}

// ---------------- 128x128 GEMM (output projection): 512 blocks = 2/CU ----------
// Cf[4096,2048] = A[4096,2048] * Wo[2048,2048]^T, fp32 epilogue. Same protocol.
// Per wave 64x32 = 4x2 frags (32 acc VGPR). LDS 64 KiB -> 2 blocks/CU.
__global__ __launch_bounds__(512, 4) void gemm_out(
    const short* __restrict__ A, const short* __restrict__ Bm,
    float* __restrict__ Cf)
{
  __shared__ __align__(16) short As[2][128 * 64];   // 32 KiB
  __shared__ __align__(16) short Bs[2][128 * 64];   // 32 KiB

  const int N = 2048, K = 2048;
  const long tileM = (long)blockIdx.y * 128;
  const long tileN = (long)blockIdx.x * 128;

  const int tid  = threadIdx.x;
  const int lane = tid & 63;
  const int quad = lane >> 4;
  const int l15  = lane & 15;
  const int wave = tid >> 6;
  const int wm   = (wave >> 2) * 64;
  const int wn   = (wave & 3) * 32;
  const int xsw  = l15 & 7;

  f32x4 acc[4][2];
#pragma unroll
  for (int i = 0; i < 4; ++i)
#pragma unroll
    for (int j = 0; j < 2; ++j) acc[i][j] = f32x4{0.f, 0.f, 0.f, 0.f};

  const int cS = (tid & 7) ^ ((tid >> 3) & 7);
  const short* gA[2]; const short* gB[2];
#pragma unroll
  for (int p = 0; p < 2; ++p) {
    gA[p] = A  + (tileM + (tid >> 3) + 64 * p) * K + cS * 8;
    gB[p] = Bm + (tileN + (tid >> 3) + 64 * p) * K + cS * 8;
  }

  auto stage = [&](int buf, int t) {
    const long ko = (long)t * 64;
    short* la = &As[buf][0];
    short* lb = &Bs[buf][0];
#pragma unroll
    for (int p = 0; p < 2; ++p) {
      gload_lds16(gA[p] + ko, la + (tid + p * 512) * 8);
      gload_lds16(gB[p] + ko, lb + (tid + p * 512) * 8);
    }
  };

  const int NT = K / 64;
  stage(0, 0);
  asm volatile("s_waitcnt vmcnt(0)" ::: "memory");
  asm volatile("s_barrier" ::: "memory");

  bf16x8 af[2][2], bfr[2][2];

  auto ldA = [&](const short* Ab, int half) {
#pragma unroll
    for (int m = 0; m < 2; ++m) {
      const int r = wm + (half * 2 + m) * 16 + l15;
#pragma unroll
      for (int kk = 0; kk < 2; ++kk)
        af[m][kk] = *(const bf16x8*)&Ab[r * 64 + (((kk * 4 + quad) ^ xsw) << 3)];
    }
  };
  auto ldB = [&](const short* Bb) {
#pragma unroll
    for (int n = 0; n < 2; ++n) {
      const int r = wn + n * 16 + l15;
#pragma unroll
      for (int kk = 0; kk < 2; ++kk)
        bfr[n][kk] = *(const bf16x8*)&Bb[r * 64 + (((kk * 4 + quad) ^ xsw) << 3)];
    }
  };
  auto mma = [&](int half) {
    __builtin_amdgcn_s_setprio(1);
#pragma unroll
    for (int m = 0; m < 2; ++m)
#pragma unroll
      for (int n = 0; n < 2; ++n)
#pragma unroll
        for (int kk = 0; kk < 2; ++kk)
          acc[half * 2 + m][n] = MFMA16(af[m][kk], bfr[n][kk], acc[half * 2 + m][n]);
    __builtin_amdgcn_s_setprio(0);
  };

  for (int t = 0; t < NT; ++t) {
    const int cur = t & 1;
    const short* Ab = &As[cur][0];
    const short* Bb = &Bs[cur][0];

    if (t + 1 < NT) stage(cur ^ 1, t + 1);
    ldB(Bb); ldA(Ab, 0); mma(0);
    asm volatile("s_barrier" ::: "memory");
    ldA(Ab, 1); mma(1);
    asm volatile("s_waitcnt vmcnt(0)" ::: "memory");
    asm volatile("s_waitcnt lgkmcnt(0)" ::: "memory");
    asm volatile("s_barrier" ::: "memory");
  }

#pragma unroll
  for (int i = 0; i < 4; ++i)
#pragma unroll
    for (int j = 0; j < 2; ++j)
#pragma unroll
      for (int r = 0; r < 4; ++r) {
        long row = tileM + wm + i * 16 + quad * 4 + r;
        long col = tileN + wn + j * 16 + l15;
        Cf[row * N + col] = acc[i][j][r];
      }
}

// ---------------- fused RoPE (Q,K in-place in Ccat) + V transpose ---------------
// Q = Ccat cols 0..2047, K = cols 2048..2559, V = cols 2560..3071 (stride 3072).
// Vectorized x8; math identical to previous (bit-identical output).
// Q scaled by (1/8)*log2(e); V^T written slot-permuted for the attn PV A-frag.
#define ROPE_BLOCKS 2560          // Q: 2048 blocks, K: 512 blocks (x8 vectorized)
__global__ void rope_vtrans_kernel(short* __restrict__ Ccat, short* __restrict__ Vt) {
  __shared__ short tile[64][65];
  if (blockIdx.x < ROPE_BLOCKS) {
    const int QT = (B_ * S_) * NH_ * 4;  // 524288 Q threads (4 groups of 8 per head)
    int t = blockIdx.x * blockDim.x + threadIdx.x;
    long base; int g; float scale; int row;
    if (t < QT) {
      row = t >> 7; int rem = t & 127, head = rem >> 2; g = rem & 3;
      base = (long)row * CSTR + head * HD_;
      scale = 0.125f * 1.44269504f;
    } else {
      int t2 = t - QT;
      row = t2 >> 5; int rem = t2 & 31, head = rem >> 2; g = rem & 3;
      base = (long)row * CSTR + 2048 + head * HD_;
      scale = 1.0f;
    }
    const int s = row & (S_ - 1);
    const int i0 = g * 8;
    union V8 { bf16x8 v; short e[8]; };
    V8 x0, x1, y0, y1;
    x0.v = *(const bf16x8*)&Ccat[base + i0];
    x1.v = *(const bf16x8*)&Ccat[base + i0 + 32];
#pragma unroll
    for (int j = 0; j < 8; ++j) {
      const int i = i0 + j;
      float invr = exp2f((float)i * -0.41524101f) * 0.15915494309f;
      float rev = (float)s * invr;
      rev -= floorf(rev);
      float ar = rev * 6.28318530718f;
      float c = __cosf(ar), sn = __sinf(ar);
      float a = bf2f(x0.e[j]);
      float b = bf2f(x1.e[j]);
      y0.e[j] = f2bf((a * c - b * sn) * scale);
      y1.e[j] = f2bf((b * c + a * sn) * scale);
    }
    *(bf16x8*)&Ccat[base + i0]      = y0.v;
    *(bf16x8*)&Ccat[base + i0 + 32] = y1.v;
  } else {
    int blk = blockIdx.x - ROPE_BLOCKS;
    int s0 = (blk & 31) * 64;
    int h  = (blk >> 5) & 7;
    int b  = blk >> 8;
    int tid = threadIdx.x;
#pragma unroll
    for (int it = 0; it < 16; ++it) {
      int idx = tid + it * 256;
      int r = idx >> 6, c = idx & 63;
      tile[r][c] = Ccat[((long)(b * S_ + s0 + r)) * CSTR + 2560 + h * HD_ + c];
    }
    __syncthreads();
#pragma unroll
    for (int it = 0; it < 16; ++it) {
      int idx = tid + it * 256;
      int d = idx >> 6, s = idx & 63;
      int slot = (s & 0x20) | (((s >> 2) & 3) << 3) | (((s >> 4) & 1) << 2) | (s & 3);
      Vt[((long)((b * NKV_ + h) * HD_ + d)) * S_ + s0 + slot] = tile[s][d];
    }
  }
}

// ---------------- Flash attention (causal, GQA), transposed-score form ----------
// 8-WAVE RE-PARTITION (R13 post-mortem): R13's 4-wave/2-frag blocks capped the
// CU at 2 blocks x 4 waves = 8 waves (25% occupancy ceiling, measured 17.6%,
// all pipes < 40% busy -> starved of independent streams per SIMD). Same
// 128-row block, same paired q-tiles (34 iterations/block), same XCD remap,
// same 2-slot protocol -- but 512 threads: EACH WAVE OWNS ONE 16-row
// q-fragment (wave w -> rows qbase + w*16 + l15). 2 blocks/CU x 8 waves =
// 16 waves/CU (4/SIMD), double the latency-hiding streams; VGPR drops to ~75
// (one fragment of state). Staging: 512 lanes x 16B = full 8 KiB K (or V)
// tile in ONE gload_lds line. Causal handling is wave-uniform: at kb==kmax
// waves 0-3 are fully masked (skip compute, keep barriers/staging), waves 4-7
// mask with thr-64; at kb==kmax-1 waves 0-3 mask with thr. Per-q-row math and
// accumulation order identical to R13 -> bit-identical output.
__global__ __launch_bounds__(512, 4) void attn_kernel(
    const short* __restrict__ Ccat, const short* __restrict__ Vt,
    short* __restrict__ O)
{
  // ---- XCD-aware index derivation (pure remap of the linear block id) ----
  const int l    = (int)blockIdx.x + 8 * (int)blockIdx.y;   // 0..511
  const int r8   = l & 7;                 // XCD residue (round-robin)
  const int m    = l >> 3;                // 0..63
  const int kvcol = r8 + 8 * (m >> 5);    // 0..15 = b*8 + hkv (2 per XCD)
  const int idx  = m & 31;                // 0..31 within column
  const int b    = kvcol >> 3;
  const int hkv  = kvcol & 7;
  const int h    = hkv * 4 + (idx >> 3);  // head within the GQA group
  const int pair = idx & 7;               // q-tile pair id: tiles {15-pair, pair}

  const int tid = threadIdx.x, lane = tid & 63, w = tid >> 6;  // w = 0..7
  const int quad = lane >> 4, l15 = lane & 15;

  __shared__ __align__(16) short Ks[2][64 * 64];   // [key][feature], chunk-swizzled
  __shared__ __align__(16) short Vs[2][64 * 64];   // [d][slot], chunk-swizzled

  const short* kg = Ccat + ((long)(b * S_)) * CSTR + 2048 + hkv * HD_;
  const short* vg = Vt + ((long)((b * NKV_ + hkv) * HD_)) * S_;

  // Staging: 512 threads cover all 64 rows (rK = tid>>3), chunk cC per row.
  const int rK = tid >> 3;                       // 0..63
  const int cC = (tid & 7) ^ (rK & 7);
  const short* kSrc = kg + (long)rK * CSTR + cC * 8;
  const short* vSrc = vg + (long)rK * S_ + cC * 8;
  short* kDst = &Ks[0][tid * 8];
  short* vDst = &Vs[0][tid * 8];

  auto stage = [&](int buf, int kb) {
    const long ko = (long)kb * 64 * CSTR;
    const long vo = (long)kb * 64;
    const int bo = buf * 4096;
    gload_lds16(kSrc + ko, kDst + bo);
    gload_lds16(vSrc + vo, vDst + bo);
  };

  const int thr   = w * 16 + l15;   // row offset within the 128-row tile (0..127)
  const bool lower = (w < 4);       // rows 0..63 vs 64..127 (wave-uniform)
  const int thrW  = lower ? thr : thr - 64;  // diagonal threshold within own half
  union U8 { uint32_t u[4]; bf16x8 v; };

  auto run_tile = [&](int qt) {
    const int kmax = 2 * qt + 1;              // last 64-key tile index
    const int qbase = qt * 128;
    const int qrow0 = qbase + w * 16;         // this wave's 16 q-rows
    const short* qb = Ccat + ((long)(b * S_ + qrow0 + l15)) * CSTR + h * HD_;
    const bf16x8 aq0 = *(const bf16x8*)(qb + quad * 8);
    const bf16x8 aq1 = *(const bf16x8*)(qb + 32 + quad * 8);

    f32x4 o[4];
#pragma unroll
    for (int i = 0; i < 4; ++i) o[i] = f32x4{0.f, 0.f, 0.f, 0.f};
    f32x4 li4 = f32x4{0.f, 0.f, 0.f, 0.f};

    // prologue: stage tile 0 (previous pass fully drained at its last barrier)
    stage(0, 0);
    asm volatile("s_waitcnt vmcnt(0)" ::: "memory");
    asm volatile("s_barrier" ::: "memory");

    int cur = 0;
    for (int kb = 0; kb <= kmax; ++kb) {
      // 1-deep prefetch into the other slot (readers finished at the end of
      // the previous iteration's lgkmcnt(0)+barrier)
      if (kb < kmax) stage(cur ^ 1, kb + 1);
      const short* Kb = &Ks[cur][0];
      const short* Vb = &Vs[cur][0];
      // wave-uniform predication: lower half fully masked at the last tile
      const bool doW = !(kb == kmax && lower);
      const bool doMask = lower ? (kb == kmax - 1) : (kb == kmax);

      if (doW) {
        // ---- Sc^T = K·Q^T ----
        f32x4 s[4];
        __builtin_amdgcn_s_setprio(1);
#pragma unroll
        for (int nt = 0; nt < 4; ++nt) {
          const int r = nt * 16 + l15;
          bf16x8 k0 = *(const bf16x8*)&Kb[(r * 8 + ((quad)     ^ (r & 7))) * 8];
          bf16x8 k1 = *(const bf16x8*)&Kb[(r * 8 + ((quad + 4) ^ (r & 7))) * 8];
          f32x4 t = f32x4{0.f, 0.f, 0.f, 0.f};
          t = MFMA16(k0, aq0, t);
          t = MFMA16(k1, aq1, t);
          s[nt] = t;
        }
        __builtin_amdgcn_s_setprio(0);

        // ---- causal mask (diagonal tile of this wave's half) ----
        if (doMask) {
#pragma unroll
          for (int nt = 0; nt < 4; ++nt) {
            const int base = nt * 16 + quad * 4;
#pragma unroll
            for (int rr = 0; rr < 4; ++rr)
              if (base + rr > thrW) s[nt][rr] = -1e30f;
          }
        }

        // ---- exp2 + pack to P^T B-fragments (registers only) ----
        U8 p[2];
#pragma unroll
        for (int kt = 0; kt < 2; ++kt) {
          float e0 = fast_exp2(s[2 * kt][0]),     e1 = fast_exp2(s[2 * kt][1]);
          float e2 = fast_exp2(s[2 * kt][2]),     e3 = fast_exp2(s[2 * kt][3]);
          float e4 = fast_exp2(s[2 * kt + 1][0]), e5 = fast_exp2(s[2 * kt + 1][1]);
          float e6 = fast_exp2(s[2 * kt + 1][2]), e7 = fast_exp2(s[2 * kt + 1][3]);
          p[kt].u[0] = f2bf_pk(e0, e1);
          p[kt].u[1] = f2bf_pk(e2, e3);
          p[kt].u[2] = f2bf_pk(e4, e5);
          p[kt].u[3] = f2bf_pk(e6, e7);
          li4 += f32x4{e0, e1, e2, e3};
          li4 += f32x4{e4, e5, e6, e7};
        }

        // ---- O^T += V^T · P^T ----
        __builtin_amdgcn_s_setprio(1);
#pragma unroll
        for (int kt = 0; kt < 2; ++kt) {
          bf16x8 vf[4];
#pragma unroll
          for (int dt = 0; dt < 4; ++dt)
            vf[dt] = *(const bf16x8*)&Vb[(dt * 16 + l15) * 64 +
                                         (((kt * 4 + quad) ^ (l15 & 7)) << 3)];
#pragma unroll
          for (int dt = 0; dt < 4; ++dt)
            o[dt] = MFMA16(vf[dt], p[kt].v, o[dt]);
        }
        __builtin_amdgcn_s_setprio(0);
      }

      // end-of-iteration: next-tile DMA landed (overlapped with the compute
      // above), my LDS reads of slot cur serviced, then collective release.
      asm volatile("s_waitcnt vmcnt(0)" ::: "memory");
      asm volatile("s_waitcnt lgkmcnt(0)" ::: "memory");
      asm volatile("s_barrier" ::: "memory");
      cur ^= 1;
    }

    // ---- epilogue: O^T C-layout -> lane holds qrow=l15, d = dt*16+quad*4+r --
    float l2 = (li4[0] + li4[1]) + (li4[2] + li4[3]);
    l2 += __shfl_xor(l2, 16, 64);
    l2 += __shfl_xor(l2, 32, 64);
    float invl = 1.0f / l2;
    long orow = (long)(b * S_ + qrow0 + l15);
#pragma unroll
    for (int dt = 0; dt < 4; ++dt) {
      uint2 st;
      st.x = f2bf_pk(o[dt][0] * invl, o[dt][1] * invl);
      st.y = f2bf_pk(o[dt][2] * invl, o[dt][3] * invl);
      *(uint2*)&O[orow * (NH_ * HD_) + h * HD_ + dt * 16 + quad * 4] = st;
    }
  };

  run_tile(15 - pair);   // long tile first
  run_tile(pair);        // short tile second -> every block = 34 iterations
}

// ---------------- launch -------------------------------------------------------
extern "C" void kernel_launch(void* const* d_in, const int* in_sizes, int n_in,
                              void* d_out, int out_size, void* d_ws, size_t ws_size,
                              hipStream_t stream) {
  const float* hs = (const float*)d_in[0];
  const float* Wq = (const float*)d_in[1];
  const float* Wk = (const float*)d_in[2];
  const float* Wv = (const float*)d_in[3];
  const float* Wo = (const float*)d_in[4];
  float* out = (float*)d_out;

  char* p = (char*)d_ws;
  auto carve = [&](size_t elems) { short* r = (short*)p; p += elems * 2; return r; };
  short* Xb   = carve(8388608);    // hidden bf16 [4096,2048]
  short* Wcat = carve(6291456);    // [Wq;Wk;Wv] rows -> [3072,2048]
  short* Wob  = carve(4194304);
  short* Ccat = carve(12582912);   // QKV-cat [4096,3072]
  short* Vtt  = carve(2097152);    // V^T [B,KV,HD,S] (slot-permuted)
  short* Om   = carve(8388608);    // attn out [4096,2048]

  short* Wqb = Wcat;               // rows 0..2047
  short* Wkb = Wcat + 4194304;     // rows 2048..2559
  short* Wvb = Wcat + 5242880;     // rows 2560..3071

  Cvt5Args ca{hs, Wq, Wk, Wv, Wo, Xb, Wqb, Wkb, Wvb, Wob};
  cvt5_kernel<<<CV4 / 256, 256, 0, stream>>>(ca);

  // QKV-cat projection: 128x192 tiles, grid 16x32 = 512 blocks = 2/CU
  gemm_qkvcat<<<dim3(16, 32), 512, 0, stream>>>(Xb, Wcat, Ccat);

  rope_vtrans_kernel<<<ROPE_BLOCKS + 512, 256, 0, stream>>>(Ccat, Vtt);

  // attention: grid (8,64) = 512 blocks x 512 threads = 2 blocks/CU x 8 waves
  // = 16 waves/CU; paired q-tiles (34 iters/block); XCD remap; 2-slot LDS
  attn_kernel<<<dim3(8, 64, 1), 512, 0, stream>>>(Ccat, Vtt, Om);

  // Output projection: 128x128 tiles, grid 16x32 = 512 blocks = 2/CU
  gemm_out<<<dim3(16, 32), 512, 0, stream>>>(Om, Wob, out);
}

// Round 15
// 260.918 us; speedup vs baseline: 1.0013x; 1.0013x over previous
//
#include <hip/hip_runtime.h>
#include <hip/hip_bf16.h>
#include <cstdint>
#include <cmath>

// Problem constants
#define B_   2
#define S_   2048
#define H_   2048
#define NH_  32
#define NKV_ 8
#define HD_  64
#define CSTR 3072   // row stride of the concatenated QKV output [4096, 3072]

using bf16x8 = __attribute__((ext_vector_type(8))) short;
using f32x4  = __attribute__((ext_vector_type(4))) float;

#define MFMA16(a, b, c) __builtin_amdgcn_mfma_f32_16x16x32_bf16((a), (b), (c), 0, 0, 0)

__device__ __forceinline__ short f2bf(float f) {   // round-nearest-even
  uint32_t u = __float_as_uint(f);
  uint32_t r = (u + 0x7fffu + ((u >> 16) & 1u)) >> 16;
  return (short)r;
}
__device__ __forceinline__ float bf2f(short s) {
  return __uint_as_float(((uint32_t)(uint16_t)s) << 16);
}
// packed 2xf32 -> 2xbf16 (hardware op when available)
__device__ __forceinline__ uint32_t f2bf_pk(float a, float b) {
#if __has_builtin(__builtin_amdgcn_cvt_pk_bf16_f32)
  auto r = __builtin_amdgcn_cvt_pk_bf16_f32(a, b);
  uint32_t u; __builtin_memcpy(&u, &r, sizeof(u));
  return u;
#else
  uint32_t ua = (__float_as_uint(a) + 0x8000u) >> 16;
  uint32_t ub = (__float_as_uint(b) + 0x8000u) >> 16;
  return ua | (ub << 16);
#endif
}
// raw v_exp_f32 (2^x)
__device__ __forceinline__ float fast_exp2(float x) {
#if __has_builtin(__builtin_amdgcn_exp2f)
  return __builtin_amdgcn_exp2f(x);
#else
  return exp2f(x);
#endif
}

__device__ __forceinline__ void gload_lds16(const void* g, void* l) {
  __builtin_amdgcn_global_load_lds((const __attribute__((address_space(1))) void*)g,
                                   (__attribute__((address_space(3))) void*)l, 16, 0, 0);
}

// ---------------- fused fp32 -> bf16 convert for all 5 tensors ------------------
struct Cvt5Args {
  const float *s0, *s1, *s2, *s3, *s4;
  short *d0, *d1, *d2, *d3, *d4;
};
#define CV0 2097152             // hs      (float4 units)
#define CV1 (CV0 + 1048576)     // Wq
#define CV2 (CV1 + 262144)      // Wk
#define CV3 (CV2 + 262144)      // Wv
#define CV4 (CV3 + 1048576)     // Wo -> total 4718592
__global__ void cvt5_kernel(Cvt5Args a) {
  int i = blockIdx.x * blockDim.x + threadIdx.x;
  const float* s; short* d; int off;
  if      (i < CV0) { s = a.s0; d = a.d0; off = i; }
  else if (i < CV1) { s = a.s1; d = a.d1; off = i - CV0; }
  else if (i < CV2) { s = a.s2; d = a.d2; off = i - CV1; }
  else if (i < CV3) { s = a.s3; d = a.d3; off = i - CV2; }
  else              { s = a.s4; d = a.d4; off = i - CV3; }
  const float4 v = ((const float4*)s)[off];
  uint2 o;
  o.x = (uint32_t)(uint16_t)f2bf(v.x) | ((uint32_t)(uint16_t)f2bf(v.y) << 16);
  o.y = (uint32_t)(uint16_t)f2bf(v.z) | ((uint32_t)(uint16_t)f2bf(v.w) << 16);
  ((uint2*)d)[off] = o;
}

// ---------------- 128x192 QKV-cat GEMM: grid 16x32 = 512 blocks = 2/CU ---------
// Ccat[4096,3072] = X[4096,2048] * Wcat[3072,2048]^T. BK=64, 512 threads =
// 8 waves (2M x 4N); per wave 64x48 output = 4x3 16x16 frags (48 acc VGPR).
// LDS = A 2x16K + B 2x24K = EXACTLY 80 KiB -> 2 blocks/CU (4 waves/SIMD).
// R7-verified: 52 us, MfmaUtil ~41, 990 TF. Cross-block overlap (m114) covers
// the end-of-tile vmcnt(0) drain. Protocol & XOR swizzle unchanged.
__global__ __launch_bounds__(512, 4) void gemm_qkvcat(
    const short* __restrict__ A, const short* __restrict__ Bcat,
    short* __restrict__ Ccat)
{
  __shared__ __align__(16) short As[2][128 * 64];   // 32 KiB
  __shared__ __align__(16) short Bs[2][192 * 64];   // 48 KiB

  const long tileM = (long)blockIdx.y * 128;
  const long tileN = (long)blockIdx.x * 192;
  const int  K = 2048;

  const int tid  = threadIdx.x;
  const int lane = tid & 63;
  const int quad = lane >> 4;
  const int l15  = lane & 15;
  const int wave = tid >> 6;
  const int wm   = (wave >> 2) * 64;      // 0 / 64
  const int wn   = (wave & 3) * 48;       // 0..144 (multiple of 16)
  const int xsw  = l15 & 7;

  f32x4 acc[4][3];
#pragma unroll
  for (int i = 0; i < 4; ++i)
#pragma unroll
    for (int j = 0; j < 3; ++j) acc[i][j] = f32x4{0.f, 0.f, 0.f, 0.f};

  // Staging: thread c = tid + 512p covers row c>>3, LDS chunk c&7 (linear dest).
  // Global source chunk = swizzle inverse. A: 2 passes (128 rows), B: 3 (192).
  const int cS = (tid & 7) ^ ((tid >> 3) & 7);
  const short* gA[2]; const short* gB[3];
#pragma unroll
  for (int p = 0; p < 2; ++p)
    gA[p] = A + (tileM + (tid >> 3) + 64 * p) * K + cS * 8;
#pragma unroll
  for (int p = 0; p < 3; ++p)
    gB[p] = Bcat + (tileN + (tid >> 3) + 64 * p) * K + cS * 8;

  auto stage = [&](int buf, int t) {
    const long ko = (long)t * 64;
    short* la = &As[buf][0];
    short* lb = &Bs[buf][0];
#pragma unroll
    for (int p = 0; p < 2; ++p)
      gload_lds16(gA[p] + ko, la + (tid + p * 512) * 8);
#pragma unroll
    for (int p = 0; p < 3; ++p)
      gload_lds16(gB[p] + ko, lb + (tid + p * 512) * 8);
  };

  const int NT = K / 64;                       // 32
  stage(0, 0);
  asm volatile("s_waitcnt vmcnt(0)" ::: "memory");
  asm volatile("s_barrier" ::: "memory");

  bf16x8 af[2][2], bfr[3][2];

  auto ldA = [&](const short* Ab, int half) {
#pragma unroll
    for (int m = 0; m < 2; ++m) {
      const int r = wm + (half * 2 + m) * 16 + l15;
#pragma unroll
      for (int kk = 0; kk < 2; ++kk)
        af[m][kk] = *(const bf16x8*)&Ab[r * 64 + (((kk * 4 + quad) ^ xsw) << 3)];
    }
  };
  auto ldB = [&](const short* Bb) {
#pragma unroll
    for (int n = 0; n < 3; ++n) {
      const int r = wn + n * 16 + l15;
#pragma unroll
      for (int kk = 0; kk < 2; ++kk)
        bfr[n][kk] = *(const bf16x8*)&Bb[r * 64 + (((kk * 4 + quad) ^ xsw) << 3)];
    }
  };
  auto mma = [&](int half) {
    __builtin_amdgcn_s_setprio(1);
#pragma unroll
    for (int m = 0; m < 2; ++m)
#pragma unroll
      for (int n = 0; n < 3; ++n)
#pragma unroll
        for (int kk = 0; kk < 2; ++kk)
          acc[half * 2 + m][n] = MFMA16(af[m][kk], bfr[n][kk], acc[half * 2 + m][n]);
    __builtin_amdgcn_s_setprio(0);
  };

  for (int t = 0; t < NT; ++t) {
    const int cur = t & 1;
    const short* Ab = &As[cur][0];
    const short* Bb = &Bs[cur][0];

    // phase 0: stage next tile, mf-half 0 (B loaded once, reused in half 1)
    if (t + 1 < NT) stage(cur ^ 1, t + 1);
    ldB(Bb); ldA(Ab, 0); mma(0);
    asm volatile("s_barrier" ::: "memory");
    // phase 1: mf-half 1
    ldA(Ab, 1); mma(1);
    asm volatile("s_waitcnt vmcnt(0)" ::: "memory");    // next-tile DMA landed
    asm volatile("s_waitcnt lgkmcnt(0)" ::: "memory");  // my reads of slot cur done
    asm volatile("s_barrier" ::: "memory");             // release slot cur
  }

#pragma unroll
  for (int i = 0; i < 4; ++i)
#pragma unroll
    for (int j = 0; j < 3; ++j)
#pragma unroll
      for (int r = 0; r < 4; ++r) {
        long row = tileM + wm + i * 16 + quad * 4 + r;
        long col = tileN + wn + j * 16 + l15;
        Ccat[row * CSTR + col] = f2bf(acc[i][j][r]);
      }
}

// ---------------- 128x128 GEMM (output projection): 512 blocks = 2/CU ----------
// Cf[4096,2048] = A[4096,2048] * Wo[2048,2048]^T, fp32 epilogue. Same protocol.
// Per wave 64x32 = 4x2 frags (32 acc VGPR). LDS 64 KiB -> 2 blocks/CU.
__global__ __launch_bounds__(512, 4) void gemm_out(
    const short* __restrict__ A, const short* __restrict__ Bm,
    float* __restrict__ Cf)
{
  __shared__ __align__(16) short As[2][128 * 64];   // 32 KiB
  __shared__ __align__(16) short Bs[2][128 * 64];   // 32 KiB

  const int N = 2048, K = 2048;
  const long tileM = (long)blockIdx.y * 128;
  const long tileN = (long)blockIdx.x * 128;

  const int tid  = threadIdx.x;
  const int lane = tid & 63;
  const int quad = lane >> 4;
  const int l15  = lane & 15;
  const int wave = tid >> 6;
  const int wm   = (wave >> 2) * 64;
  const int wn   = (wave & 3) * 32;
  const int xsw  = l15 & 7;

  f32x4 acc[4][2];
#pragma unroll
  for (int i = 0; i < 4; ++i)
#pragma unroll
    for (int j = 0; j < 2; ++j) acc[i][j] = f32x4{0.f, 0.f, 0.f, 0.f};

  const int cS = (tid & 7) ^ ((tid >> 3) & 7);
  const short* gA[2]; const short* gB[2];
#pragma unroll
  for (int p = 0; p < 2; ++p) {
    gA[p] = A  + (tileM + (tid >> 3) + 64 * p) * K + cS * 8;
    gB[p] = Bm + (tileN + (tid >> 3) + 64 * p) * K + cS * 8;
  }

  auto stage = [&](int buf, int t) {
    const long ko = (long)t * 64;
    short* la = &As[buf][0];
    short* lb = &Bs[buf][0];
#pragma unroll
    for (int p = 0; p < 2; ++p) {
      gload_lds16(gA[p] + ko, la + (tid + p * 512) * 8);
      gload_lds16(gB[p] + ko, lb + (tid + p * 512) * 8);
    }
  };

  const int NT = K / 64;
  stage(0, 0);
  asm volatile("s_waitcnt vmcnt(0)" ::: "memory");
  asm volatile("s_barrier" ::: "memory");

  bf16x8 af[2][2], bfr[2][2];

  auto ldA = [&](const short* Ab, int half) {
#pragma unroll
    for (int m = 0; m < 2; ++m) {
      const int r = wm + (half * 2 + m) * 16 + l15;
#pragma unroll
      for (int kk = 0; kk < 2; ++kk)
        af[m][kk] = *(const bf16x8*)&Ab[r * 64 + (((kk * 4 + quad) ^ xsw) << 3)];
    }
  };
  auto ldB = [&](const short* Bb) {
#pragma unroll
    for (int n = 0; n < 2; ++n) {
      const int r = wn + n * 16 + l15;
#pragma unroll
      for (int kk = 0; kk < 2; ++kk)
        bfr[n][kk] = *(const bf16x8*)&Bb[r * 64 + (((kk * 4 + quad) ^ xsw) << 3)];
    }
  };
  auto mma = [&](int half) {
    __builtin_amdgcn_s_setprio(1);
#pragma unroll
    for (int m = 0; m < 2; ++m)
#pragma unroll
      for (int n = 0; n < 2; ++n)
#pragma unroll
        for (int kk = 0; kk < 2; ++kk)
          acc[half * 2 + m][n] = MFMA16(af[m][kk], bfr[n][kk], acc[half * 2 + m][n]);
    __builtin_amdgcn_s_setprio(0);
  };

  for (int t = 0; t < NT; ++t) {
    const int cur = t & 1;
    const short* Ab = &As[cur][0];
    const short* Bb = &Bs[cur][0];

    if (t + 1 < NT) stage(cur ^ 1, t + 1);
    ldB(Bb); ldA(Ab, 0); mma(0);
    asm volatile("s_barrier" ::: "memory");
    ldA(Ab, 1); mma(1);
    asm volatile("s_waitcnt vmcnt(0)" ::: "memory");
    asm volatile("s_waitcnt lgkmcnt(0)" ::: "memory");
    asm volatile("s_barrier" ::: "memory");
  }

#pragma unroll
  for (int i = 0; i < 4; ++i)
#pragma unroll
    for (int j = 0; j < 2; ++j)
#pragma unroll
      for (int r = 0; r < 4; ++r) {
        long row = tileM + wm + i * 16 + quad * 4 + r;
        long col = tileN + wn + j * 16 + l15;
        Cf[row * N + col] = acc[i][j][r];
      }
}

// ---------------- fused RoPE (Q,K in-place in Ccat) + V transpose ---------------
// Q = Ccat cols 0..2047, K = cols 2048..2559, V = cols 2560..3071 (stride 3072).
// Vectorized x8; math identical to previous (bit-identical output).
// Q scaled by (1/8)*log2(e); V^T written slot-permuted for the attn PV A-frag.
#define ROPE_BLOCKS 2560          // Q: 2048 blocks, K: 512 blocks (x8 vectorized)
__global__ void rope_vtrans_kernel(short* __restrict__ Ccat, short* __restrict__ Vt) {
  __shared__ short tile[64][65];
  if (blockIdx.x < ROPE_BLOCKS) {
    const int QT = (B_ * S_) * NH_ * 4;  // 524288 Q threads (4 groups of 8 per head)
    int t = blockIdx.x * blockDim.x + threadIdx.x;
    long base; int g; float scale; int row;
    if (t < QT) {
      row = t >> 7; int rem = t & 127, head = rem >> 2; g = rem & 3;
      base = (long)row * CSTR + head * HD_;
      scale = 0.125f * 1.44269504f;
    } else {
      int t2 = t - QT;
      row = t2 >> 5; int rem = t2 & 31, head = rem >> 2; g = rem & 3;
      base = (long)row * CSTR + 2048 + head * HD_;
      scale = 1.0f;
    }
    const int s = row & (S_ - 1);
    const int i0 = g * 8;
    union V8 { bf16x8 v; short e[8]; };
    V8 x0, x1, y0, y1;
    x0.v = *(const bf16x8*)&Ccat[base + i0];
    x1.v = *(const bf16x8*)&Ccat[base + i0 + 32];
#pragma unroll
    for (int j = 0; j < 8; ++j) {
      const int i = i0 + j;
      float invr = exp2f((float)i * -0.41524101f) * 0.15915494309f;
      float rev = (float)s * invr;
      rev -= floorf(rev);
      float ar = rev * 6.28318530718f;
      float c = __cosf(ar), sn = __sinf(ar);
      float a = bf2f(x0.e[j]);
      float b = bf2f(x1.e[j]);
      y0.e[j] = f2bf((a * c - b * sn) * scale);
      y1.e[j] = f2bf((b * c + a * sn) * scale);
    }
    *(bf16x8*)&Ccat[base + i0]      = y0.v;
    *(bf16x8*)&Ccat[base + i0 + 32] = y1.v;
  } else {
    int blk = blockIdx.x - ROPE_BLOCKS;
    int s0 = (blk & 31) * 64;
    int h  = (blk >> 5) & 7;
    int b  = blk >> 8;
    int tid = threadIdx.x;
#pragma unroll
    for (int it = 0; it < 16; ++it) {
      int idx = tid + it * 256;
      int r = idx >> 6, c = idx & 63;
      tile[r][c] = Ccat[((long)(b * S_ + s0 + r)) * CSTR + 2560 + h * HD_ + c];
    }
    __syncthreads();
#pragma unroll
    for (int it = 0; it < 16; ++it) {
      int idx = tid + it * 256;
      int d = idx >> 6, s = idx & 63;
      int slot = (s & 0x20) | (((s >> 2) & 3) << 3) | (((s >> 4) & 1) << 2) | (s & 3);
      Vt[((long)((b * NKV_ + h) * HD_ + d)) * S_ + s0 + slot] = tile[s][d];
    }
  }
}

// ---------------- Flash attention (causal, GQA), transposed-score form ----------
// DOUBLE-GRANULARITY SYNC (R14 post-mortem): doubling waves/CU (17.6 -> 34.5%
// occupancy) bought only 1.3 us -> the limiter is intra-block phase-locking:
// a vmcnt(0)+lgkmcnt(0)+barrier every 64-key tile (34/pass) keeps the 8 waves
// in lockstep bursts. This round: 128 KEYS PER BARRIER INTERVAL -- each staged
// slot holds TWO 64x64 K subtiles + TWO 64x64 V subtiles (16+16 KiB), computed
// back-to-back between barriers (~600 cy of independent work per wave, 4-load
// DMA hides under it; barrier count halves to 17/pass, always exact since
// kmax+1 = 2qt+2 is even). LDS 2 x 32 KiB = 64 KiB -> still 2 blocks/CU x
// 8 waves = 16 waves/CU. Same 2-slot protocol proof at doubled granularity;
// subtiles processed in identical kb order -> bit-identical numerics.
// Retained: 8-wave/1-frag partition, paired q-tiles (uniform length), XCD
// remap (K/V L2-hot, FETCH 12.4 MB).
__global__ __launch_bounds__(512, 4) void attn_kernel(
    const short* __restrict__ Ccat, const short* __restrict__ Vt,
    short* __restrict__ O)
{
  // ---- XCD-aware index derivation (pure remap of the linear block id) ----
  const int l    = (int)blockIdx.x + 8 * (int)blockIdx.y;   // 0..511
  const int r8   = l & 7;                 // XCD residue (round-robin)
  const int m    = l >> 3;                // 0..63
  const int kvcol = r8 + 8 * (m >> 5);    // 0..15 = b*8 + hkv (2 per XCD)
  const int idx  = m & 31;                // 0..31 within column
  const int b    = kvcol >> 3;
  const int hkv  = kvcol & 7;
  const int h    = hkv * 4 + (idx >> 3);  // head within the GQA group
  const int pair = idx & 7;               // q-tile pair id: tiles {15-pair, pair}

  const int tid = threadIdx.x, lane = tid & 63, w = tid >> 6;  // w = 0..7
  const int quad = lane >> 4, l15 = lane & 15;

  __shared__ __align__(16) short Ks[2][8192];   // 2 slots x two 64x64 K subtiles
  __shared__ __align__(16) short Vs[2][8192];   // 2 slots x two 64x64 V subtiles

  const short* kg = Ccat + ((long)(b * S_)) * CSTR + 2048 + hkv * HD_;
  const short* vg = Vt + ((long)((b * NKV_ + hkv) * HD_)) * S_;

  // Staging: 512 threads cover 64 rows (rK = tid>>3) x 8 chunks per subtile.
  const int rK = tid >> 3;                       // 0..63
  const int cC = (tid & 7) ^ (rK & 7);
  const short* kSrc = kg + (long)rK * CSTR + cC * 8;
  const short* vSrc = vg + (long)rK * S_ + cC * 8;
  short* kDst = &Ks[0][tid * 8];
  short* vDst = &Vs[0][tid * 8];

  // stage one 128-key DOUBLE tile (4 gload_lds lines of 8 KiB each)
  auto stage = [&](int buf, int kb2) {
    const long k0 = (long)kb2 * 128;
    const int bo = buf * 8192;
    gload_lds16(kSrc + k0 * CSTR,        kDst + bo);          // K sub0
    gload_lds16(kSrc + (k0 + 64) * CSTR, kDst + bo + 4096);   // K sub1
    gload_lds16(vSrc + k0,               vDst + bo);          // V sub0
    gload_lds16(vSrc + k0 + 64,          vDst + bo + 4096);   // V sub1
  };

  const int thr   = w * 16 + l15;   // row offset within the 128-row tile (0..127)
  const bool lower = (w < 4);       // rows 0..63 vs 64..127 (wave-uniform)
  const int thrW  = lower ? thr : thr - 64;  // diagonal threshold within own half
  union U8 { uint32_t u[4]; bf16x8 v; };

  auto run_tile = [&](int qt) {
    const int kmax = 2 * qt + 1;              // last 64-key tile index
    const int ND   = qt + 1;                  // double-iterations (exact, no tail)
    const int qbase = qt * 128;
    const int qrow0 = qbase + w * 16;         // this wave's 16 q-rows
    const short* qb = Ccat + ((long)(b * S_ + qrow0 + l15)) * CSTR + h * HD_;
    const bf16x8 aq0 = *(const bf16x8*)(qb + quad * 8);
    const bf16x8 aq1 = *(const bf16x8*)(qb + 32 + quad * 8);

    f32x4 o[4];
#pragma unroll
    for (int i = 0; i < 4; ++i) o[i] = f32x4{0.f, 0.f, 0.f, 0.f};
    f32x4 li4 = f32x4{0.f, 0.f, 0.f, 0.f};

    // prologue: stage double-tile 0 (previous pass drained at its last barrier)
    stage(0, 0);
    asm volatile("s_waitcnt vmcnt(0)" ::: "memory");
    asm volatile("s_barrier" ::: "memory");

    int cur = 0;
    for (int kb2 = 0; kb2 < ND; ++kb2) {
      // 1-deep prefetch into the other slot (readers finished at the end of
      // the previous interval's lgkmcnt(0)+barrier)
      if (kb2 + 1 < ND) stage(cur ^ 1, kb2 + 1);

#pragma unroll
      for (int sub = 0; sub < 2; ++sub) {
        const int kb = 2 * kb2 + sub;
        const short* Kb = &Ks[cur][sub * 4096];
        const short* Vb = &Vs[cur][sub * 4096];
        // wave-uniform predication: lower half fully masked at the last tile
        const bool doW = !(kb == kmax && lower);
        const bool doMask = lower ? (kb == kmax - 1) : (kb == kmax);

        if (doW) {
          // ---- Sc^T = K·Q^T ----
          f32x4 s[4];
          __builtin_amdgcn_s_setprio(1);
#pragma unroll
          for (int nt = 0; nt < 4; ++nt) {
            const int r = nt * 16 + l15;
            bf16x8 k0 = *(const bf16x8*)&Kb[(r * 8 + ((quad)     ^ (r & 7))) * 8];
            bf16x8 k1 = *(const bf16x8*)&Kb[(r * 8 + ((quad + 4) ^ (r & 7))) * 8];
            f32x4 t = f32x4{0.f, 0.f, 0.f, 0.f};
            t = MFMA16(k0, aq0, t);
            t = MFMA16(k1, aq1, t);
            s[nt] = t;
          }
          __builtin_amdgcn_s_setprio(0);

          // ---- causal mask (diagonal tile of this wave's half) ----
          if (doMask) {
#pragma unroll
            for (int nt = 0; nt < 4; ++nt) {
              const int base = nt * 16 + quad * 4;
#pragma unroll
              for (int rr = 0; rr < 4; ++rr)
                if (base + rr > thrW) s[nt][rr] = -1e30f;
            }
          }

          // ---- exp2 + pack to P^T B-fragments (registers only) ----
          U8 p[2];
#pragma unroll
          for (int kt = 0; kt < 2; ++kt) {
            float e0 = fast_exp2(s[2 * kt][0]),     e1 = fast_exp2(s[2 * kt][1]);
            float e2 = fast_exp2(s[2 * kt][2]),     e3 = fast_exp2(s[2 * kt][3]);
            float e4 = fast_exp2(s[2 * kt + 1][0]), e5 = fast_exp2(s[2 * kt + 1][1]);
            float e6 = fast_exp2(s[2 * kt + 1][2]), e7 = fast_exp2(s[2 * kt + 1][3]);
            p[kt].u[0] = f2bf_pk(e0, e1);
            p[kt].u[1] = f2bf_pk(e2, e3);
            p[kt].u[2] = f2bf_pk(e4, e5);
            p[kt].u[3] = f2bf_pk(e6, e7);
            li4 += f32x4{e0, e1, e2, e3};
            li4 += f32x4{e4, e5, e6, e7};
          }

          // ---- O^T += V^T · P^T ----
          __builtin_amdgcn_s_setprio(1);
#pragma unroll
          for (int kt = 0; kt < 2; ++kt) {
            bf16x8 vf[4];
#pragma unroll
            for (int dt = 0; dt < 4; ++dt)
              vf[dt] = *(const bf16x8*)&Vb[(dt * 16 + l15) * 64 +
                                           (((kt * 4 + quad) ^ (l15 & 7)) << 3)];
#pragma unroll
            for (int dt = 0; dt < 4; ++dt)
              o[dt] = MFMA16(vf[dt], p[kt].v, o[dt]);
          }
          __builtin_amdgcn_s_setprio(0);
        }
      }

      // end-of-interval: next double-tile DMA landed (overlapped with the two
      // subtile computes above), my LDS reads serviced, collective release.
      asm volatile("s_waitcnt vmcnt(0)" ::: "memory");
      asm volatile("s_waitcnt lgkmcnt(0)" ::: "memory");
      asm volatile("s_barrier" ::: "memory");
      cur ^= 1;
    }

    // ---- epilogue: O^T C-layout -> lane holds qrow=l15, d = dt*16+quad*4+r --
    float l2 = (li4[0] + li4[1]) + (li4[2] + li4[3]);
    l2 += __shfl_xor(l2, 16, 64);
    l2 += __shfl_xor(l2, 32, 64);
    float invl = 1.0f / l2;
    long orow = (long)(b * S_ + qrow0 + l15);
#pragma unroll
    for (int dt = 0; dt < 4; ++dt) {
      uint2 st;
      st.x = f2bf_pk(o[dt][0] * invl, o[dt][1] * invl);
      st.y = f2bf_pk(o[dt][2] * invl, o[dt][3] * invl);
      *(uint2*)&O[orow * (NH_ * HD_) + h * HD_ + dt * 16 + quad * 4] = st;
    }
  };

  run_tile(15 - pair);   // long tile first
  run_tile(pair);        // short tile second -> every block = 17 intervals
}

// ---------------- launch -------------------------------------------------------
extern "C" void kernel_launch(void* const* d_in, const int* in_sizes, int n_in,
                              void* d_out, int out_size, void* d_ws, size_t ws_size,
                              hipStream_t stream) {
  const float* hs = (const float*)d_in[0];
  const float* Wq = (const float*)d_in[1];
  const float* Wk = (const float*)d_in[2];
  const float* Wv = (const float*)d_in[3];
  const float* Wo = (const float*)d_in[4];
  float* out = (float*)d_out;

  char* p = (char*)d_ws;
  auto carve = [&](size_t elems) { short* r = (short*)p; p += elems * 2; return r; };
  short* Xb   = carve(8388608);    // hidden bf16 [4096,2048]
  short* Wcat = carve(6291456);    // [Wq;Wk;Wv] rows -> [3072,2048]
  short* Wob  = carve(4194304);
  short* Ccat = carve(12582912);   // QKV-cat [4096,3072]
  short* Vtt  = carve(2097152);    // V^T [B,KV,HD,S] (slot-permuted)
  short* Om   = carve(8388608);    // attn out [4096,2048]

  short* Wqb = Wcat;               // rows 0..2047
  short* Wkb = Wcat + 4194304;     // rows 2048..2559
  short* Wvb = Wcat + 5242880;     // rows 2560..3071

  Cvt5Args ca{hs, Wq, Wk, Wv, Wo, Xb, Wqb, Wkb, Wvb, Wob};
  cvt5_kernel<<<CV4 / 256, 256, 0, stream>>>(ca);

  // QKV-cat projection: 128x192 tiles, grid 16x32 = 512 blocks = 2/CU
  gemm_qkvcat<<<dim3(16, 32), 512, 0, stream>>>(Xb, Wcat, Ccat);

  rope_vtrans_kernel<<<ROPE_BLOCKS + 512, 256, 0, stream>>>(Ccat, Vtt);

  // attention: grid (8,64) = 512 blocks x 512 threads = 2 blocks/CU x 8 waves;
  // paired q-tiles, 128 keys per barrier interval (17 intervals/block)
  attn_kernel<<<dim3(8, 64, 1), 512, 0, stream>>>(Ccat, Vtt, Om);

  // Output projection: 128x128 tiles, grid 16x32 = 512 blocks = 2/CU
  gemm_out<<<dim3(16, 32), 512, 0, stream>>>(Om, Wob, out);
}